// Round 1
// baseline (585.749 us; speedup 1.0000x reference)
//
#include <hip/hip_runtime.h>
#include <cstdint>

// ---------- common helpers ----------

typedef __bf16 bf16x8 __attribute__((ext_vector_type(8)));
typedef float  f32x4  __attribute__((ext_vector_type(4)));

__device__ __forceinline__ unsigned short f2b(float f) {
    union { float f; unsigned u; } v; v.f = f;
    unsigned r = v.u + 0x7FFFu + ((v.u >> 16) & 1u);   // RNE
    return (unsigned short)(r >> 16);
}

__device__ __forceinline__ void async_copy16(void* lds, const void* g) {
    __builtin_amdgcn_global_load_lds(
        (const __attribute__((address_space(1))) unsigned int*)g,
        (__attribute__((address_space(3))) unsigned int*)lds,
        16, 0, 0);
}

// ---------- conversion kernels ----------

// x fp32 -> bf16, 4 elems/thread, grid*256*4 == 8192*4096
__global__ __launch_bounds__(256) void k_cvt(const float* __restrict__ in,
                                             unsigned short* __restrict__ out) {
    int i = blockIdx.x * 256 + threadIdx.x;
    float4 f = ((const float4*)in)[i];
    ushort4 o = make_ushort4(f2b(f.x), f2b(f.y), f2b(f.z), f2b(f.w));
    ((ushort4*)out)[i] = o;
}

// in: [R][C] fp32 row-major  ->  out: [C][R] bf16 (transposed)
__global__ __launch_bounds__(256) void k_transpose_cvt(const float* __restrict__ in,
                                                       unsigned short* __restrict__ out,
                                                       int R, int C) {
    __shared__ float tile[32][33];
    int bc = blockIdx.x * 32;   // col base in input
    int br = blockIdx.y * 32;   // row base in input
    int tx = threadIdx.x, ty = threadIdx.y;   // (32, 8)
    #pragma unroll
    for (int i = 0; i < 32; i += 8)
        tile[ty + i][tx] = in[(size_t)(br + ty + i) * C + bc + tx];
    __syncthreads();
    #pragma unroll
    for (int i = 0; i < 32; i += 8)
        out[(size_t)(bc + ty + i) * R + br + tx] = f2b(tile[tx][ty + i]);
}

// ---------- main GEMM (m97-style): C[M][N] = A[M][K] * B^T[N][K] ----------
// MODE 0: +bias, tanh, store bf16   (GEMM1 -> T)
// MODE 1: +bias, store fp32         (GEMM2 -> a)
// MODE 2: atomicAdd fp32 (split-K)  (GEMM3 -> h)

#define BM 128
#define BN 128
#define BK 32

template <int MODE>
__global__ __launch_bounds__(256)
void k_gemm(const unsigned short* __restrict__ A,
            const unsigned short* __restrict__ B,
            const float* __restrict__ bias,
            void* __restrict__ Out, int ldout,
            int lda, int ldb, int k_len) {
    __shared__ __align__(16) unsigned short As[BM * BK];
    __shared__ __align__(16) unsigned short Bs[BN * BK];

    const int tid  = threadIdx.x;
    const int wave = tid >> 6;
    const int lane = tid & 63;
    const int quad = lane >> 4;
    const int l16  = lane & 15;
    const int wr   = wave >> 1;     // 0..1 row half
    const int wc   = wave & 1;      // 0..1 col half

    const int bn = blockIdx.x;
    const int bm = blockIdx.y;
    const int kz = blockIdx.z;

    const unsigned short* Ag = A + (size_t)(bm * BM) * lda + (size_t)kz * k_len;
    const unsigned short* Bg = B + (size_t)(bn * BN) * ldb + (size_t)kz * k_len;

    f32x4 acc[4][4];
    #pragma unroll
    for (int i = 0; i < 4; i++)
        #pragma unroll
        for (int j = 0; j < 4; j++)
            acc[i][j] = f32x4{0.f, 0.f, 0.f, 0.f};

    // staging: 512 x 16B chunks per tile; chunk ch -> row ch/4, 16B-seg ch%4
    const int ch0 = wave * 128 + lane;
    const int ch1 = ch0 + 64;
    const int r0 = ch0 >> 2, c0 = ch0 & 3;
    const int r1 = ch1 >> 2, c1 = ch1 & 3;
    unsigned short* AsBase0 = &As[(wave * 128) * 8];
    unsigned short* AsBase1 = &As[(wave * 128 + 64) * 8];
    unsigned short* BsBase0 = &Bs[(wave * 128) * 8];
    unsigned short* BsBase1 = &Bs[(wave * 128 + 64) * 8];

    for (int k0 = 0; k0 < k_len; k0 += BK) {
        async_copy16(AsBase0, Ag + (size_t)r0 * lda + k0 + c0 * 8);
        async_copy16(AsBase1, Ag + (size_t)r1 * lda + k0 + c1 * 8);
        async_copy16(BsBase0, Bg + (size_t)r0 * ldb + k0 + c0 * 8);
        async_copy16(BsBase1, Bg + (size_t)r1 * ldb + k0 + c1 * 8);
        asm volatile("s_waitcnt vmcnt(0)" ::: "memory");
        __syncthreads();

        bf16x8 av[4], bv[4];
        #pragma unroll
        for (int i = 0; i < 4; i++)
            av[i] = *(const bf16x8*)&As[(wr * 64 + i * 16 + l16) * BK + quad * 8];
        #pragma unroll
        for (int j = 0; j < 4; j++)
            bv[j] = *(const bf16x8*)&Bs[(wc * 64 + j * 16 + l16) * BK + quad * 8];
        #pragma unroll
        for (int i = 0; i < 4; i++)
            #pragma unroll
            for (int j = 0; j < 4; j++)
                acc[i][j] = __builtin_amdgcn_mfma_f32_16x16x32_bf16(av[i], bv[j], acc[i][j], 0, 0, 0);
        __syncthreads();
    }

    // epilogue: C/D layout col = lane&15, row = quad*4 + reg (m89/m91 verified)
    #pragma unroll
    for (int i = 0; i < 4; i++) {
        int rbase = bm * BM + wr * 64 + i * 16 + quad * 4;
        #pragma unroll
        for (int j = 0; j < 4; j++) {
            int col = bn * BN + wc * 64 + j * 16 + l16;
            #pragma unroll
            for (int r = 0; r < 4; r++) {
                int row = rbase + r;
                float val = acc[i][j][r];
                if (MODE == 0) {
                    val += bias[col];
                    ((unsigned short*)Out)[(size_t)row * ldout + col] = f2b(tanhf(val));
                } else if (MODE == 1) {
                    val += bias[col];
                    ((float*)Out)[(size_t)row * ldout + col] = val;
                } else {
                    atomicAdd(&((float*)Out)[(size_t)row * ldout + col], val);
                }
            }
        }
    }
}

// ---------- sparsemax + gating ----------
// one block per row; bisection on f(tau) = sum(max(z - tau, 0)) - 1
__global__ __launch_bounds__(256)
void k_sparsemax(const float* __restrict__ a, const float* __restrict__ x,
                 unsigned short* __restrict__ wout) {
    const int row = blockIdx.x;
    const int tid = threadIdx.x;
    const float* ar = a + (size_t)row * 4096;

    float v[16];
    #pragma unroll
    for (int i = 0; i < 16; i++) v[i] = ar[tid + i * 256];

    // row max
    float m = v[0];
    #pragma unroll
    for (int i = 1; i < 16; i++) m = fmaxf(m, v[i]);
    #pragma unroll
    for (int off = 32; off >= 1; off >>= 1) m = fmaxf(m, __shfl_xor(m, off));

    __shared__ float red[4];
    if ((tid & 63) == 0) red[tid >> 6] = m;
    __syncthreads();
    m = fmaxf(fmaxf(red[0], red[1]), fmaxf(red[2], red[3]));

    float lo = m - 1.0f, hi = m;
    for (int it = 0; it < 30; ++it) {
        float mid = 0.5f * (lo + hi);
        float s = 0.f;
        #pragma unroll
        for (int i = 0; i < 16; i++) s += fmaxf(v[i] - mid, 0.f);
        #pragma unroll
        for (int off = 32; off >= 1; off >>= 1) s += __shfl_xor(s, off);
        __syncthreads();                       // protect red before overwrite
        if ((tid & 63) == 0) red[tid >> 6] = s;
        __syncthreads();
        s = red[0] + red[1] + red[2] + red[3]; // uniform across block
        if (s > 1.0f) lo = mid; else hi = mid;
    }
    float tau = 0.5f * (lo + hi);

    const float* xr = x + (size_t)row * 4096;
    #pragma unroll
    for (int i = 0; i < 16; i++) {
        int d = tid + i * 256;
        float w = fmaxf(v[i] - tau, 0.f) * xr[d];
        wout[(size_t)row * 4096 + d] = f2b(w);
    }
}

// ---------- final: out = relu(h + bc1) @ Wc2 + bc2 ----------
__global__ __launch_bounds__(256)
void k_final(const float* __restrict__ h, const float* __restrict__ bc1,
             const float* __restrict__ Wc2, const float* __restrict__ bc2,
             float* __restrict__ out) {
    __shared__ float w2s[128 * 16];
    __shared__ float b1s[128];
    int tid = threadIdx.x;
    for (int i = tid; i < 2048; i += 256) w2s[i] = Wc2[i];
    if (tid < 128) b1s[tid] = bc1[tid];
    __syncthreads();

    int wave = tid >> 6, lane = tid & 63;
    int row = blockIdx.x * 4 + wave;
    int c = lane & 15, hq = lane >> 4;
    const float* hr = h + (size_t)row * 128;
    float acc = 0.f;
    #pragma unroll
    for (int t = 0; t < 32; ++t) {
        int hidx = hq * 32 + t;
        float hv = fmaxf(hr[hidx] + b1s[hidx], 0.f);
        acc += hv * w2s[hidx * 16 + c];
    }
    acc += __shfl_xor(acc, 16);
    acc += __shfl_xor(acc, 32);
    if (hq == 0) out[(size_t)row * 16 + c] = acc + bc2[c];
}

// ---------- launch ----------

extern "C" void kernel_launch(void* const* d_in, const int* in_sizes, int n_in,
                              void* d_out, int out_size, void* d_ws, size_t ws_size,
                              hipStream_t stream) {
    (void)in_sizes; (void)n_in; (void)out_size; (void)ws_size;
    const float* x   = (const float*)d_in[0];
    const float* W1  = (const float*)d_in[1];
    const float* b1  = (const float*)d_in[2];
    const float* W2  = (const float*)d_in[3];
    const float* b2  = (const float*)d_in[4];
    const float* Wc1 = (const float*)d_in[5];
    const float* bc1 = (const float*)d_in[6];
    const float* Wc2 = (const float*)d_in[7];
    const float* bc2 = (const float*)d_in[8];
    float* out = (float*)d_out;

    char* ws = (char*)d_ws;
    unsigned short* xb   = (unsigned short*)(ws);                  // 64 MB [8192][4096] bf16 (later: weighted)
    unsigned short* W1t  = (unsigned short*)(ws + (64ll  << 20));  // 8 MB  [1024][4096]
    unsigned short* Tb   = (unsigned short*)(ws + (72ll  << 20));  // 16 MB [8192][1024]
    unsigned short* W2t  = (unsigned short*)(ws + (88ll  << 20));  // 8 MB  [4096][1024]
    float*          ab   = (float*)         (ws + (96ll  << 20));  // 128 MB [8192][4096] fp32 (later: h)
    unsigned short* Wc1t = (unsigned short*)(ws + (224ll << 20));  // 1 MB  [128][4096]
    float*          hb   = (float*)         (ws + (96ll  << 20));  // 4 MB  [8192][128] (reuses ab)
    unsigned short* wb   = xb;                                     // weighted reuses xb

    dim3 tb(32, 8);
    k_cvt<<<32768, 256, 0, stream>>>(x, xb);
    k_transpose_cvt<<<dim3(1024 / 32, 4096 / 32), tb, 0, stream>>>(W1, W1t, 4096, 1024);
    k_transpose_cvt<<<dim3(4096 / 32, 1024 / 32), tb, 0, stream>>>(W2, W2t, 1024, 4096);
    k_transpose_cvt<<<dim3(128 / 32, 4096 / 32), tb, 0, stream>>>(Wc1, Wc1t, 4096, 128);

    // T = tanh(x @ W1 + b1)   [8192][1024] bf16
    k_gemm<0><<<dim3(8, 64, 1), 256, 0, stream>>>(xb, W1t, b1, Tb, 1024, 4096, 4096, 4096);
    // a = T @ W2 + b2         [8192][4096] fp32
    k_gemm<1><<<dim3(32, 64, 1), 256, 0, stream>>>(Tb, W2t, b2, ab, 4096, 1024, 1024, 1024);
    // weighted = x * sparsemax(a)  -> bf16
    k_sparsemax<<<8192, 256, 0, stream>>>(ab, x, wb);
    // h = weighted @ Wc1 (split-K=8, atomic accumulate)
    hipMemsetAsync(hb, 0, (size_t)8192 * 128 * 4, stream);
    k_gemm<2><<<dim3(1, 64, 8), 256, 0, stream>>>(wb, Wc1t, nullptr, hb, 128, 4096, 4096, 512);
    // out = relu(h + bc1) @ Wc2 + bc2
    k_final<<<2048, 256, 0, stream>>>(hb, bc1, Wc2, bc2, out);
}

// Round 2
// 535.256 us; speedup vs baseline: 1.0943x; 1.0943x over previous
//
#include <hip/hip_runtime.h>
#include <cstdint>

// ---------- common helpers ----------

typedef __bf16 bf16x8 __attribute__((ext_vector_type(8)));
typedef float  f32x4  __attribute__((ext_vector_type(4)));
typedef unsigned short u16x8 __attribute__((ext_vector_type(8)));

__device__ __forceinline__ unsigned short f2b(float f) {
    union { float f; unsigned u; } v; v.f = f;
    unsigned r = v.u + 0x7FFFu + ((v.u >> 16) & 1u);   // RNE
    return (unsigned short)(r >> 16);
}

__device__ __forceinline__ float b2f(unsigned short u) {
    union { unsigned u; float f; } v; v.u = ((unsigned)u) << 16;
    return v.f;
}

__device__ __forceinline__ void async_copy16(void* lds, const void* g) {
    __builtin_amdgcn_global_load_lds(
        (const __attribute__((address_space(1))) unsigned int*)g,
        (__attribute__((address_space(3))) unsigned int*)lds,
        16, 0, 0);
}

// ---------- conversion kernels ----------

__global__ __launch_bounds__(256) void k_cvt(const float* __restrict__ in,
                                             unsigned short* __restrict__ out) {
    int i = blockIdx.x * 256 + threadIdx.x;
    float4 f = ((const float4*)in)[i];
    ushort4 o = make_ushort4(f2b(f.x), f2b(f.y), f2b(f.z), f2b(f.w));
    ((ushort4*)out)[i] = o;
}

// in: [R][C] fp32 row-major  ->  out: [C][R] bf16 (transposed)
__global__ __launch_bounds__(256) void k_transpose_cvt(const float* __restrict__ in,
                                                       unsigned short* __restrict__ out,
                                                       int R, int C) {
    __shared__ float tile[32][33];
    int bc = blockIdx.x * 32;
    int br = blockIdx.y * 32;
    int tx = threadIdx.x, ty = threadIdx.y;   // (32, 8)
    #pragma unroll
    for (int i = 0; i < 32; i += 8)
        tile[ty + i][tx] = in[(size_t)(br + ty + i) * C + bc + tx];
    __syncthreads();
    #pragma unroll
    for (int i = 0; i < 32; i += 8)
        out[(size_t)(bc + ty + i) * R + br + tx] = f2b(tile[tx][ty + i]);
}

// ---------- GEMM1: 512-thread 128x128 tile, bias+tanh -> bf16 ----------
// C[M][N] = A[M][K] * B^T[N][K]; 8 waves, each 64x32 of the tile.

__global__ __launch_bounds__(512, 4)
void k_gemm_tanh(const unsigned short* __restrict__ A,
                 const unsigned short* __restrict__ B,
                 const float* __restrict__ bias,
                 unsigned short* __restrict__ Out, int ldout,
                 int lda, int ldb, int k_len) {
    __shared__ __align__(16) unsigned short As[128 * 32];
    __shared__ __align__(16) unsigned short Bs[128 * 32];

    const int tid  = threadIdx.x;
    const int wave = tid >> 6;      // 0..7
    const int lane = tid & 63;
    const int quad = lane >> 4;
    const int l16  = lane & 15;
    const int wr   = wave >> 2;     // 0..1 : 64-row half
    const int wc   = wave & 3;      // 0..3 : 32-col quarter

    const int bn = blockIdx.x;
    const int bm = blockIdx.y;

    const unsigned short* Ag = A + (size_t)(bm * 128) * lda;
    const unsigned short* Bg = B + (size_t)(bn * 128) * ldb;

    f32x4 acc[4][2];
    #pragma unroll
    for (int i = 0; i < 4; i++)
        #pragma unroll
        for (int j = 0; j < 2; j++)
            acc[i][j] = f32x4{0.f, 0.f, 0.f, 0.f};

    // staging: 512 chunks of 16B per tile; thread -> chunk (wave*64+lane)
    const int ch = wave * 64 + lane;
    const int sr = ch >> 2, sc = ch & 3;
    unsigned short* AsBase = &As[(wave * 64) * 8];
    unsigned short* BsBase = &Bs[(wave * 64) * 8];

    for (int k0 = 0; k0 < k_len; k0 += 32) {
        async_copy16(AsBase, Ag + (size_t)sr * lda + k0 + sc * 8);
        async_copy16(BsBase, Bg + (size_t)sr * ldb + k0 + sc * 8);
        asm volatile("s_waitcnt vmcnt(0)" ::: "memory");
        __syncthreads();

        bf16x8 av[4], bv[2];
        #pragma unroll
        for (int i = 0; i < 4; i++)
            av[i] = *(const bf16x8*)&As[(wr * 64 + i * 16 + l16) * 32 + quad * 8];
        #pragma unroll
        for (int j = 0; j < 2; j++)
            bv[j] = *(const bf16x8*)&Bs[(wc * 32 + j * 16 + l16) * 32 + quad * 8];
        #pragma unroll
        for (int i = 0; i < 4; i++)
            #pragma unroll
            for (int j = 0; j < 2; j++)
                acc[i][j] = __builtin_amdgcn_mfma_f32_16x16x32_bf16(av[i], bv[j], acc[i][j], 0, 0, 0);
        __syncthreads();
    }

    #pragma unroll
    for (int i = 0; i < 4; i++) {
        int rbase = bm * 128 + wr * 64 + i * 16 + quad * 4;
        #pragma unroll
        for (int j = 0; j < 2; j++) {
            int col = bn * 128 + wc * 32 + j * 16 + l16;
            float bc = bias[col];
            #pragma unroll
            for (int r = 0; r < 4; r++)
                Out[(size_t)(rbase + r) * ldout + col] = f2b(tanhf(acc[i][j][r] + bc));
        }
    }
}

// ---------- 256-thread GEMM (m97-style) ----------
// MODE 1: +bias, store bf16   (GEMM2 -> a)
// MODE 2: atomicAdd fp32      (GEMM3 -> h, split-K)

template <int MODE>
__global__ __launch_bounds__(256)
void k_gemm(const unsigned short* __restrict__ A,
            const unsigned short* __restrict__ B,
            const float* __restrict__ bias,
            void* __restrict__ Out, int ldout,
            int lda, int ldb, int k_len) {
    __shared__ __align__(16) unsigned short As[128 * 32];
    __shared__ __align__(16) unsigned short Bs[128 * 32];

    const int tid  = threadIdx.x;
    const int wave = tid >> 6;
    const int lane = tid & 63;
    const int quad = lane >> 4;
    const int l16  = lane & 15;
    const int wr   = wave >> 1;
    const int wc   = wave & 1;

    const int bn = blockIdx.x;
    const int bm = blockIdx.y;
    const int kz = blockIdx.z;

    const unsigned short* Ag = A + (size_t)(bm * 128) * lda + (size_t)kz * k_len;
    const unsigned short* Bg = B + (size_t)(bn * 128) * ldb + (size_t)kz * k_len;

    f32x4 acc[4][4];
    #pragma unroll
    for (int i = 0; i < 4; i++)
        #pragma unroll
        for (int j = 0; j < 4; j++)
            acc[i][j] = f32x4{0.f, 0.f, 0.f, 0.f};

    const int ch0 = wave * 128 + lane;
    const int ch1 = ch0 + 64;
    const int r0 = ch0 >> 2, c0 = ch0 & 3;
    const int r1 = ch1 >> 2, c1 = ch1 & 3;
    unsigned short* AsBase0 = &As[(wave * 128) * 8];
    unsigned short* AsBase1 = &As[(wave * 128 + 64) * 8];
    unsigned short* BsBase0 = &Bs[(wave * 128) * 8];
    unsigned short* BsBase1 = &Bs[(wave * 128 + 64) * 8];

    for (int k0 = 0; k0 < k_len; k0 += 32) {
        async_copy16(AsBase0, Ag + (size_t)r0 * lda + k0 + c0 * 8);
        async_copy16(AsBase1, Ag + (size_t)r1 * lda + k0 + c1 * 8);
        async_copy16(BsBase0, Bg + (size_t)r0 * ldb + k0 + c0 * 8);
        async_copy16(BsBase1, Bg + (size_t)r1 * ldb + k0 + c1 * 8);
        asm volatile("s_waitcnt vmcnt(0)" ::: "memory");
        __syncthreads();

        bf16x8 av[4], bv[4];
        #pragma unroll
        for (int i = 0; i < 4; i++)
            av[i] = *(const bf16x8*)&As[(wr * 64 + i * 16 + l16) * 32 + quad * 8];
        #pragma unroll
        for (int j = 0; j < 4; j++)
            bv[j] = *(const bf16x8*)&Bs[(wc * 64 + j * 16 + l16) * 32 + quad * 8];
        #pragma unroll
        for (int i = 0; i < 4; i++)
            #pragma unroll
            for (int j = 0; j < 4; j++)
                acc[i][j] = __builtin_amdgcn_mfma_f32_16x16x32_bf16(av[i], bv[j], acc[i][j], 0, 0, 0);
        __syncthreads();
    }

    #pragma unroll
    for (int i = 0; i < 4; i++) {
        int rbase = bm * 128 + wr * 64 + i * 16 + quad * 4;
        #pragma unroll
        for (int j = 0; j < 4; j++) {
            int col = bn * 128 + wc * 64 + j * 16 + l16;
            #pragma unroll
            for (int r = 0; r < 4; r++) {
                int row = rbase + r;
                float val = acc[i][j][r];
                if (MODE == 1) {
                    val += bias[col];
                    ((unsigned short*)Out)[(size_t)row * ldout + col] = f2b(val);
                } else {
                    atomicAdd(&((float*)Out)[(size_t)row * ldout + col], val);
                }
            }
        }
    }
}

// ---------- sparsemax + gating (bf16 in/out, vectorized) ----------
// one block per row; 18-iter bisection on f(tau) = sum(max(z-tau,0)) - 1

__global__ __launch_bounds__(256)
void k_sparsemax(const unsigned short* __restrict__ a,
                 const unsigned short* __restrict__ xb,
                 unsigned short* __restrict__ wout) {
    const int row = blockIdx.x;
    const int tid = threadIdx.x;
    const u16x8* ar = (const u16x8*)(a + (size_t)row * 4096);

    u16x8 u0 = ar[tid], u1 = ar[tid + 256];
    float v[16];
    #pragma unroll
    for (int i = 0; i < 8; i++) { v[i] = b2f(u0[i]); v[8 + i] = b2f(u1[i]); }

    // row max
    float m = v[0];
    #pragma unroll
    for (int i = 1; i < 16; i++) m = fmaxf(m, v[i]);
    #pragma unroll
    for (int off = 32; off >= 1; off >>= 1) m = fmaxf(m, __shfl_xor(m, off));

    __shared__ float red[2][4];
    const int wave = tid >> 6;
    if ((tid & 63) == 0) red[0][wave] = m;
    __syncthreads();
    m = fmaxf(fmaxf(red[0][0], red[0][1]), fmaxf(red[0][2], red[0][3]));

    float lo = m - 1.0f, hi = m;
    #pragma unroll 1
    for (int it = 0; it < 18; ++it) {
        float mid = 0.5f * (lo + hi);
        float s = 0.f;
        #pragma unroll
        for (int i = 0; i < 16; i++) s += fmaxf(v[i] - mid, 0.f);
        #pragma unroll
        for (int off = 32; off >= 1; off >>= 1) s += __shfl_xor(s, off);
        int p = (it & 1) ^ 1;                 // alternate buffers; max used [0]
        if ((tid & 63) == 0) red[p][wave] = s;
        __syncthreads();
        s = red[p][0] + red[p][1] + red[p][2] + red[p][3];
        if (s > 1.0f) lo = mid; else hi = mid;
    }
    float tau = 0.5f * (lo + hi);

    const u16x8* xr = (const u16x8*)(xb + (size_t)row * 4096);
    u16x8 x0 = xr[tid], x1 = xr[tid + 256];
    u16x8 o0, o1;
    #pragma unroll
    for (int i = 0; i < 8; i++) {
        o0[i] = f2b(fmaxf(v[i] - tau, 0.f) * b2f(x0[i]));
        o1[i] = f2b(fmaxf(v[8 + i] - tau, 0.f) * b2f(x1[i]));
    }
    u16x8* wr_ = (u16x8*)(wout + (size_t)row * 4096);
    wr_[tid] = o0;
    wr_[tid + 256] = o1;
}

// ---------- final: out = relu(h + bc1) @ Wc2 + bc2 ----------
__global__ __launch_bounds__(256)
void k_final(const float* __restrict__ h, const float* __restrict__ bc1,
             const float* __restrict__ Wc2, const float* __restrict__ bc2,
             float* __restrict__ out) {
    __shared__ float w2s[128 * 16];
    __shared__ float b1s[128];
    int tid = threadIdx.x;
    for (int i = tid; i < 2048; i += 256) w2s[i] = Wc2[i];
    if (tid < 128) b1s[tid] = bc1[tid];
    __syncthreads();

    int wave = tid >> 6, lane = tid & 63;
    int row = blockIdx.x * 4 + wave;
    int c = lane & 15, hq = lane >> 4;
    const float* hr = h + (size_t)row * 128;
    float acc = 0.f;
    #pragma unroll
    for (int t = 0; t < 32; ++t) {
        int hidx = hq * 32 + t;
        float hv = fmaxf(hr[hidx] + b1s[hidx], 0.f);
        acc += hv * w2s[hidx * 16 + c];
    }
    acc += __shfl_xor(acc, 16);
    acc += __shfl_xor(acc, 32);
    if (hq == 0) out[(size_t)row * 16 + c] = acc + bc2[c];
}

// ---------- launch ----------

extern "C" void kernel_launch(void* const* d_in, const int* in_sizes, int n_in,
                              void* d_out, int out_size, void* d_ws, size_t ws_size,
                              hipStream_t stream) {
    (void)in_sizes; (void)n_in; (void)out_size; (void)ws_size;
    const float* x   = (const float*)d_in[0];
    const float* W1  = (const float*)d_in[1];
    const float* b1  = (const float*)d_in[2];
    const float* W2  = (const float*)d_in[3];
    const float* b2  = (const float*)d_in[4];
    const float* Wc1 = (const float*)d_in[5];
    const float* bc1 = (const float*)d_in[6];
    const float* Wc2 = (const float*)d_in[7];
    const float* bc2 = (const float*)d_in[8];
    float* out = (float*)d_out;

    char* ws = (char*)d_ws;
    unsigned short* xb   = (unsigned short*)(ws);                  // 64 MB [8192][4096] bf16 (later: weighted)
    unsigned short* W1t  = (unsigned short*)(ws + (64ll  << 20));  // 8 MB  [1024][4096]
    unsigned short* Tb   = (unsigned short*)(ws + (72ll  << 20));  // 16 MB [8192][1024]
    unsigned short* W2t  = (unsigned short*)(ws + (88ll  << 20));  // 8 MB  [4096][1024]
    unsigned short* abf  = (unsigned short*)(ws + (96ll  << 20));  // 64 MB [8192][4096] bf16
    unsigned short* Wc1t = (unsigned short*)(ws + (160ll << 20));  // 1 MB  [128][4096]
    float*          hb   = (float*)         (ws + (162ll << 20));  // 4 MB  [8192][128]
    unsigned short* wb   = xb;                                     // weighted reuses xb

    dim3 tb(32, 8);
    k_cvt<<<32768, 256, 0, stream>>>(x, xb);
    k_transpose_cvt<<<dim3(1024 / 32, 4096 / 32), tb, 0, stream>>>(W1, W1t, 4096, 1024);
    k_transpose_cvt<<<dim3(4096 / 32, 1024 / 32), tb, 0, stream>>>(W2, W2t, 1024, 4096);
    k_transpose_cvt<<<dim3(128 / 32, 4096 / 32), tb, 0, stream>>>(Wc1, Wc1t, 4096, 128);

    // T = tanh(x @ W1 + b1)   [8192][1024] bf16  (512-thread blocks)
    k_gemm_tanh<<<dim3(8, 64), 512, 0, stream>>>(xb, W1t, b1, Tb, 1024, 4096, 4096, 4096);
    // a = T @ W2 + b2         [8192][4096] bf16
    k_gemm<1><<<dim3(32, 64, 1), 256, 0, stream>>>(Tb, W2t, b2, abf, 4096, 1024, 1024, 1024);
    // weighted = x * sparsemax(a)  -> bf16 (in place over xb)
    k_sparsemax<<<8192, 256, 0, stream>>>(abf, xb, wb);
    // h = weighted @ Wc1 (split-K=8, atomic accumulate)
    hipMemsetAsync(hb, 0, (size_t)8192 * 128 * 4, stream);
    k_gemm<2><<<dim3(1, 64, 8), 256, 0, stream>>>(wb, Wc1t, nullptr, hb, 128, 4096, 4096, 512);
    // out = relu(h + bc1) @ Wc2 + bc2
    k_final<<<2048, 256, 0, stream>>>(hb, bc1, Wc2, bc2, out);
}